// Round 2
// baseline (167.378 us; speedup 1.0000x reference)
//
#include <hip/hip_runtime.h>
#include <math.h>

// Problem shape (fixed by reference setup_inputs)
constexpr int B = 64;
constexpr int C = 13;
constexpr int HW = 128 * 128;               // 16384
constexpr long long NTOT = (long long)B * C * HW;   // 13,631,488
constexpr long long NSAMP = (long long)B * HW;      // 1,048,576

// Output layout (concatenated flat, all read back as float32)
constexpr long long COMMIT_OFF = NTOT;
constexpr long long ENT_OFF = NTOT + 1;
constexpr long long IDX_OFF = NTOT + 2;

constexpr int THREADS = 256;
constexpr int VEC = 4;
constexpr int CHUNK = THREADS * VEC;        // 1024 hw positions per block
constexpr int BLOCKS_PER_B = HW / CHUNK;    // 16
constexpr int NBLK = B * BLOCKS_PER_B;      // 1024 blocks
constexpr int NACC = 15;                    // [0]=commit, [1]=entropy, [2..14]=p0 per channel
constexpr int SLOT = 16;                    // padded stride for per-block partials in d_ws

// counter sits past the 64 KiB partials region, in its own cache line
constexpr size_t COUNTER_BYTE_OFF = (size_t)NBLK * SLOT * sizeof(float);  // 65536

// native clang vector type — required by __builtin_nontemporal_store
typedef float nfloat4 __attribute__((ext_vector_type(4)));

// Single kernel, non-cooperative. Phase 1 is the Round-0-verified math,
// unchanged. The final reduction is run by whichever block finishes last
// (agent-scope atomic counter election — no co-residency assumption, no
// dispatch-order assumption; all cross-block data moves via agent-scope
// atomics, per Guideline 16).
__global__ __launch_bounds__(THREADS, 4) void lfq_main(const float* __restrict__ z,
                                                       float* __restrict__ out,
                                                       float* __restrict__ part,
                                                       unsigned int* __restrict__ counter) {
    constexpr float kLog2e4 = 5.7707801635558535f;  // 4*log2(e)
    constexpr float kLn2 = 0.6931471805599453f;

    __shared__ float red[THREADS / 64][NACC];

    const int bid = blockIdx.x;
    const int b = bid / BLOCKS_PER_B;
    const int j = bid % BLOCKS_PER_B;
    const int hw0 = j * CHUNK + (int)threadIdx.x * VEC;

    float cm_s = 0.0f;
    float ent_s = 0.0f;
    float p0_s[C];
#pragma unroll
    for (int c = 0; c < C; ++c) p0_s[c] = 0.0f;
    int idx[VEC] = {0, 0, 0, 0};

    const float* zb = z + (size_t)b * C * HW + hw0;
    float* zq = out + (size_t)b * C * HW + hw0;

#pragma unroll
    for (int c = 0; c < C; ++c) {
        const float4 v = *reinterpret_cast<const float4*>(zb + (size_t)c * HW);
        float zz[VEC] = {v.x, v.y, v.z, v.w};
        float qq[VEC];
#pragma unroll
        for (int k = 0; k < VEC; ++k) {
            const float zv = zz[k];
            const bool pos = (zv > 0.0f);
            qq[k] = pos ? 1.0f : -1.0f;
            const float az = fabsf(zv);
            // (q - z)^2 == (|z| - 1)^2 since q = sign(z)
            const float dm = az - 1.0f;
            cm_s = fmaf(dm, dm, cm_s);
            // binary entropy of p = sigmoid(4z):
            //   H = log1p(e) + 4|z| * sigmoid(-4|z|),  e = exp(-4|z|)
            const float e = __builtin_amdgcn_exp2f(-kLog2e4 * az);   // v_exp_f32
            const float ope = 1.0f + e;
            const float sp = __builtin_amdgcn_logf(ope) * kLn2;      // v_log_f32
            const float ps = e * __builtin_amdgcn_rcpf(ope);         // sigmoid(-4|z|)
            ent_s += fmaf(4.0f * az, ps, sp);
            p0_s[c] += pos ? (1.0f - ps) : ps;                       // p0 = sigmoid(4z)
            if (pos) idx[k] |= (1 << (C - 1 - c));                   // MSB = channel 0
        }
        nfloat4 qv = {qq[0], qq[1], qq[2], qq[3]};
        // non-temporal: stream outputs past L2/L3 so the input stays cache-resident
        __builtin_nontemporal_store(qv, reinterpret_cast<nfloat4*>(zq + (size_t)c * HW));
    }

    // bit-packed indices, stored as float values (exact up to 8191)
    nfloat4 fi = {(float)idx[0], (float)idx[1], (float)idx[2], (float)idx[3]};
    __builtin_nontemporal_store(fi, reinterpret_cast<nfloat4*>(out + IDX_OFF + (size_t)b * HW + hw0));

    // block reduction of 15 partials -> per-block slot in workspace
    float vals[NACC];
    vals[0] = cm_s;
    vals[1] = ent_s;
#pragma unroll
    for (int c = 0; c < C; ++c) vals[2 + c] = p0_s[c];
#pragma unroll
    for (int off = 32; off > 0; off >>= 1) {
#pragma unroll
        for (int k = 0; k < NACC; ++k) vals[k] += __shfl_down(vals[k], off);
    }
    const int wave = threadIdx.x >> 6;
    const int lane = threadIdx.x & 63;
    if (lane == 0) {
#pragma unroll
        for (int k = 0; k < NACC; ++k) red[wave][k] = vals[k];
    }
    __syncthreads();
    if (threadIdx.x < NACC) {
        float s = 0.0f;
#pragma unroll
        for (int w = 0; w < THREADS / 64; ++w) s += red[w][threadIdx.x];
        // agent-scope atomic store: visible to the elected block's atomic loads
        __hip_atomic_store(&part[(size_t)bid * SLOT + threadIdx.x], s,
                           __ATOMIC_RELAXED, __HIP_MEMORY_SCOPE_AGENT);
    }

    // ---- last-block election ----
    __shared__ int amLast;
    __syncthreads();  // all partial stores issued before the release-RMW below
    if (threadIdx.x == 0) {
        unsigned int old = __hip_atomic_fetch_add(counter, 1u,
                                                  __ATOMIC_ACQ_REL, __HIP_MEMORY_SCOPE_AGENT);
        amLast = (old == (unsigned int)(NBLK - 1));
    }
    __syncthreads();
    if (!amLast) return;

    // ---- final reduction: 256 threads, 4 partial slots each ----
    const int t = threadIdx.x;  // 0..255
    float fv[NACC];
#pragma unroll
    for (int k = 0; k < NACC; ++k) fv[k] = 0.0f;
#pragma unroll
    for (int s4 = 0; s4 < NBLK / THREADS; ++s4) {
        const float* p = part + (size_t)(s4 * THREADS + t) * SLOT;
#pragma unroll
        for (int k = 0; k < NACC; ++k)
            fv[k] += __hip_atomic_load(&p[k], __ATOMIC_RELAXED, __HIP_MEMORY_SCOPE_AGENT);
    }
#pragma unroll
    for (int off = 32; off > 0; off >>= 1) {
#pragma unroll
        for (int k = 0; k < NACC; ++k) fv[k] += __shfl_down(fv[k], off);
    }
    __syncthreads();  // red[] reuse: phase-1 reads are done (amLast sync), order the overwrite
    if (lane == 0) {
#pragma unroll
        for (int k = 0; k < NACC; ++k) red[wave][k] = fv[k];
    }
    __syncthreads();
    __shared__ double accs[NACC];
    if (t < NACC) {
        double s = 0.0;
#pragma unroll
        for (int w = 0; w < THREADS / 64; ++w) s += (double)red[w][t];
        accs[t] = s;
    }
    __syncthreads();
    __shared__ double ment[C];
    if (t < C) {
        const double mp0 = accs[2 + t] / (double)NSAMP;
        const double mp1 = 1.0 - mp0;
        ment[t] = -(mp0 * log(mp0) + mp1 * log(mp1));  // 13 lanes, one SIMT log pass
    }
    __syncthreads();
    if (t == 0) {
        double me = 0.0;
#pragma unroll
        for (int c = 0; c < C; ++c) me += ment[c];
        me /= (double)C;
        const double commit = accs[0] / (double)NTOT;
        const double ent = accs[1] / (double)NTOT;
        out[COMMIT_OFF] = (float)(0.1 * 1.25 * commit);  // COMMIT_MULT * (1 + BETA)
        out[ENT_OFF] = (float)(0.1 * (ent - me));        // ENT_MULT
    }
}

extern "C" void kernel_launch(void* const* d_in, const int* in_sizes, int n_in,
                              void* d_out, int out_size, void* d_ws, size_t ws_size,
                              hipStream_t stream) {
    const float* z = (const float*)d_in[0];
    float* out = (float*)d_out;
    float* part = (float*)d_ws;
    unsigned int* counter = (unsigned int*)((char*)d_ws + COUNTER_BYTE_OFF);

    // d_ws is re-poisoned by the harness every iteration: zero the 4-byte counter.
    hipMemsetAsync((void*)counter, 0, sizeof(unsigned int), stream);
    lfq_main<<<NBLK, THREADS, 0, stream>>>(z, out, part, counter);
}

// Round 3
// 111.614 us; speedup vs baseline: 1.4996x; 1.4996x over previous
//
#include <hip/hip_runtime.h>
#include <math.h>

// Problem shape (fixed by reference setup_inputs)
constexpr int B = 64;
constexpr int C = 13;
constexpr int HW = 128 * 128;               // 16384
constexpr long long NTOT = (long long)B * C * HW;   // 13,631,488
constexpr long long NSAMP = (long long)B * HW;      // 1,048,576

// Output layout (concatenated flat, all read back as float32)
constexpr long long COMMIT_OFF = NTOT;
constexpr long long ENT_OFF = NTOT + 1;
constexpr long long IDX_OFF = NTOT + 2;

constexpr int THREADS = 256;
constexpr int VEC = 4;
constexpr int CHUNK = THREADS * VEC;        // 1024 hw positions per block
constexpr int BLOCKS_PER_B = HW / CHUNK;    // 16
constexpr int NBLK = B * BLOCKS_PER_B;      // 1024 blocks
constexpr int NACC = 15;                    // [0]=commit, [1]=entropy, [2..14]=p0 per channel
constexpr int SLOT = 16;                    // padded stride for per-block partials in d_ws

// native clang vector type — required by __builtin_nontemporal_store
typedef float nfloat4 __attribute__((ext_vector_type(4)));

__global__ __launch_bounds__(THREADS, 4) void lfq_main(const float* __restrict__ z,
                                                       float* __restrict__ out,
                                                       float* __restrict__ part) {
    constexpr float kLog2e4 = 5.7707801635558535f;  // 4*log2(e)
    constexpr float kLn2 = 0.6931471805599453f;

    const int bid = blockIdx.x;
    const int b = bid / BLOCKS_PER_B;
    const int j = bid % BLOCKS_PER_B;
    const int hw0 = j * CHUNK + (int)threadIdx.x * VEC;

    float cm_s = 0.0f;
    float ent_s = 0.0f;
    float p0_s[C];
#pragma unroll
    for (int c = 0; c < C; ++c) p0_s[c] = 0.0f;
    int idx[VEC] = {0, 0, 0, 0};

    const float* zb = z + (size_t)b * C * HW + hw0;
    float* zq = out + (size_t)b * C * HW + hw0;

    // ---- load phase: all 13 channel float4s in flight per thread ----
    // (Round-2 profile showed VGPR_Count=40 -> compiler was NOT hoisting these;
    //  per-thread MLP was ~1. Explicit preload gives 13-deep load pipelining.)
    float4 v[C];
#pragma unroll
    for (int c = 0; c < C; ++c) {
        v[c] = *reinterpret_cast<const float4*>(zb + (size_t)c * HW);
    }

    // ---- compute + store phase (math identical to the verified kernel) ----
#pragma unroll
    for (int c = 0; c < C; ++c) {
        float zz[VEC] = {v[c].x, v[c].y, v[c].z, v[c].w};
        float qq[VEC];
#pragma unroll
        for (int k = 0; k < VEC; ++k) {
            const float zv = zz[k];
            const bool pos = (zv > 0.0f);
            qq[k] = pos ? 1.0f : -1.0f;
            const float az = fabsf(zv);
            // (q - z)^2 == (|z| - 1)^2 since q = sign(z)
            const float dm = az - 1.0f;
            cm_s = fmaf(dm, dm, cm_s);
            // binary entropy of p = sigmoid(4z):
            //   H = log1p(e) + 4|z| * sigmoid(-4|z|),  e = exp(-4|z|)
            const float e = __builtin_amdgcn_exp2f(-kLog2e4 * az);   // v_exp_f32
            const float ope = 1.0f + e;
            const float sp = __builtin_amdgcn_logf(ope) * kLn2;      // v_log_f32
            const float ps = e * __builtin_amdgcn_rcpf(ope);         // sigmoid(-4|z|)
            ent_s += fmaf(4.0f * az, ps, sp);
            p0_s[c] += pos ? (1.0f - ps) : ps;                       // p0 = sigmoid(4z)
            if (pos) idx[k] |= (1 << (C - 1 - c));                   // MSB = channel 0
        }
        nfloat4 qv = {qq[0], qq[1], qq[2], qq[3]};
        // non-temporal: stream outputs past L2/L3 so the input stays cache-resident
        __builtin_nontemporal_store(qv, reinterpret_cast<nfloat4*>(zq + (size_t)c * HW));
    }

    // bit-packed indices, stored as float values (exact up to 8191)
    nfloat4 fi = {(float)idx[0], (float)idx[1], (float)idx[2], (float)idx[3]};
    __builtin_nontemporal_store(fi, reinterpret_cast<nfloat4*>(out + IDX_OFF + (size_t)b * HW + hw0));

    // block reduction of 15 partials -> per-block slot in workspace (no atomics)
    float vals[NACC];
    vals[0] = cm_s;
    vals[1] = ent_s;
#pragma unroll
    for (int c = 0; c < C; ++c) vals[2 + c] = p0_s[c];
#pragma unroll
    for (int off = 32; off > 0; off >>= 1) {
#pragma unroll
        for (int k = 0; k < NACC; ++k) vals[k] += __shfl_down(vals[k], off);
    }
    __shared__ float red[THREADS / 64][NACC];
    const int wave = threadIdx.x >> 6;
    const int lane = threadIdx.x & 63;
    if (lane == 0) {
#pragma unroll
        for (int k = 0; k < NACC; ++k) red[wave][k] = vals[k];
    }
    __syncthreads();
    if (threadIdx.x < NACC) {
        float s = 0.0f;
#pragma unroll
        for (int w = 0; w < THREADS / 64; ++w) s += red[w][threadIdx.x];
        part[(size_t)bid * SLOT + threadIdx.x] = s;
    }
}

// One block, one thread per lfq_main block; reduces 1024 x 15 partials.
// Tail parallelized: 13 double logs run SIMT-concurrently instead of serially.
__global__ __launch_bounds__(NBLK) void lfq_final(const float* __restrict__ part,
                                                  float* __restrict__ out) {
    const int t = threadIdx.x;  // 0..1023
    float vals[NACC];
    const float* p = part + (size_t)t * SLOT;
#pragma unroll
    for (int k = 0; k < NACC; ++k) vals[k] = p[k];
#pragma unroll
    for (int off = 32; off > 0; off >>= 1) {
#pragma unroll
        for (int k = 0; k < NACC; ++k) vals[k] += __shfl_down(vals[k], off);
    }
    __shared__ float red[NBLK / 64][NACC];
    const int wave = t >> 6;
    const int lane = t & 63;
    if (lane == 0) {
#pragma unroll
        for (int k = 0; k < NACC; ++k) red[wave][k] = vals[k];
    }
    __syncthreads();
    __shared__ double accs[NACC];
    if (t < NACC) {
        double s = 0.0;
#pragma unroll
        for (int w = 0; w < NBLK / 64; ++w) s += (double)red[w][t];
        accs[t] = s;
    }
    __syncthreads();
    __shared__ double ment[C];
    if (t < C) {
        const double mp0 = accs[2 + t] / (double)NSAMP;
        const double mp1 = 1.0 - mp0;
        ment[t] = -(mp0 * log(mp0) + mp1 * log(mp1));  // 13 lanes, one SIMT log pass
    }
    __syncthreads();
    if (t == 0) {
        double me = 0.0;
#pragma unroll
        for (int c = 0; c < C; ++c) me += ment[c];
        me /= (double)C;
        const double commit = accs[0] / (double)NTOT;
        const double ent = accs[1] / (double)NTOT;
        out[COMMIT_OFF] = (float)(0.1 * 1.25 * commit);  // COMMIT_MULT * (1 + BETA)
        out[ENT_OFF] = (float)(0.1 * (ent - me));        // ENT_MULT
    }
}

extern "C" void kernel_launch(void* const* d_in, const int* in_sizes, int n_in,
                              void* d_out, int out_size, void* d_ws, size_t ws_size,
                              hipStream_t stream) {
    const float* z = (const float*)d_in[0];
    float* out = (float*)d_out;
    float* part = (float*)d_ws;

    lfq_main<<<NBLK, THREADS, 0, stream>>>(z, out, part);
    lfq_final<<<1, NBLK, 0, stream>>>(part, out);
}

// Round 4
// 111.277 us; speedup vs baseline: 1.5042x; 1.0030x over previous
//
#include <hip/hip_runtime.h>
#include <math.h>

// Problem shape (fixed by reference setup_inputs)
constexpr int B = 64;
constexpr int C = 13;
constexpr int HW = 128 * 128;               // 16384
constexpr long long NTOT = (long long)B * C * HW;   // 13,631,488
constexpr long long NSAMP = (long long)B * HW;      // 1,048,576

// Output layout (concatenated flat, all read back as float32)
constexpr long long COMMIT_OFF = NTOT;
constexpr long long ENT_OFF = NTOT + 1;
constexpr long long IDX_OFF = NTOT + 2;

constexpr int THREADS = 256;
constexpr int VEC = 2;                      // was 4: halve per-thread work, double grid
constexpr int CHUNK = THREADS * VEC;        // 512 hw positions per block
constexpr int BLOCKS_PER_B = HW / CHUNK;    // 32
constexpr int NBLK = B * BLOCKS_PER_B;      // 2048 blocks -> 8 blocks/CU = 32 waves/CU
constexpr int NACC = 15;                    // [0]=commit, [1]=entropy, [2..14]=p0 per channel
constexpr int SLOT = 16;                    // padded stride for per-block partials in d_ws

// native clang vector types — required by __builtin_nontemporal_store
typedef float nfloat2 __attribute__((ext_vector_type(2)));

// TLP experiment: Round-3 showed per-thread load pipelining (ILP) is NOT the
// limiter; this round doubles resident waves/CU (16 -> 32) instead.
// __launch_bounds__(256, 8): 8 waves/EU -> caps VGPR at 64 so 8 blocks/CU fit.
__global__ __launch_bounds__(THREADS, 8) void lfq_main(const float* __restrict__ z,
                                                       float* __restrict__ out,
                                                       float* __restrict__ part) {
    constexpr float kLog2e4 = 5.7707801635558535f;  // 4*log2(e)
    constexpr float kLn2 = 0.6931471805599453f;

    const int bid = blockIdx.x;
    const int b = bid / BLOCKS_PER_B;
    const int j = bid % BLOCKS_PER_B;
    const int hw0 = j * CHUNK + (int)threadIdx.x * VEC;

    float cm_s = 0.0f;
    float ent_s = 0.0f;
    float p0_s[C];
#pragma unroll
    for (int c = 0; c < C; ++c) p0_s[c] = 0.0f;
    int idx[VEC] = {0, 0};

    const float* zb = z + (size_t)b * C * HW + hw0;
    float* zq = out + (size_t)b * C * HW + hw0;

#pragma unroll
    for (int c = 0; c < C; ++c) {
        const float2 v = *reinterpret_cast<const float2*>(zb + (size_t)c * HW);
        float zz[VEC] = {v.x, v.y};
        float qq[VEC];
#pragma unroll
        for (int k = 0; k < VEC; ++k) {
            const float zv = zz[k];
            const bool pos = (zv > 0.0f);
            qq[k] = pos ? 1.0f : -1.0f;
            const float az = fabsf(zv);
            // (q - z)^2 == (|z| - 1)^2 since q = sign(z)
            const float dm = az - 1.0f;
            cm_s = fmaf(dm, dm, cm_s);
            // binary entropy of p = sigmoid(4z):
            //   H = log1p(e) + 4|z| * sigmoid(-4|z|),  e = exp(-4|z|)
            const float e = __builtin_amdgcn_exp2f(-kLog2e4 * az);   // v_exp_f32
            const float ope = 1.0f + e;
            const float sp = __builtin_amdgcn_logf(ope) * kLn2;      // v_log_f32
            const float ps = e * __builtin_amdgcn_rcpf(ope);         // sigmoid(-4|z|)
            ent_s += fmaf(4.0f * az, ps, sp);
            p0_s[c] += pos ? (1.0f - ps) : ps;                       // p0 = sigmoid(4z)
            if (pos) idx[k] |= (1 << (C - 1 - c));                   // MSB = channel 0
        }
        nfloat2 qv = {qq[0], qq[1]};
        // non-temporal: stream outputs past L2/L3 so the input stays cache-resident
        __builtin_nontemporal_store(qv, reinterpret_cast<nfloat2*>(zq + (size_t)c * HW));
    }

    // bit-packed indices, stored as float values (exact up to 8191)
    nfloat2 fi = {(float)idx[0], (float)idx[1]};
    __builtin_nontemporal_store(fi, reinterpret_cast<nfloat2*>(out + IDX_OFF + (size_t)b * HW + hw0));

    // block reduction of 15 partials -> per-block slot in workspace (no atomics)
    float vals[NACC];
    vals[0] = cm_s;
    vals[1] = ent_s;
#pragma unroll
    for (int c = 0; c < C; ++c) vals[2 + c] = p0_s[c];
#pragma unroll
    for (int off = 32; off > 0; off >>= 1) {
#pragma unroll
        for (int k = 0; k < NACC; ++k) vals[k] += __shfl_down(vals[k], off);
    }
    __shared__ float red[THREADS / 64][NACC];
    const int wave = threadIdx.x >> 6;
    const int lane = threadIdx.x & 63;
    if (lane == 0) {
#pragma unroll
        for (int k = 0; k < NACC; ++k) red[wave][k] = vals[k];
    }
    __syncthreads();
    if (threadIdx.x < NACC) {
        float s = 0.0f;
#pragma unroll
        for (int w = 0; w < THREADS / 64; ++w) s += red[w][threadIdx.x];
        part[(size_t)bid * SLOT + threadIdx.x] = s;
    }
}

// One block of 1024 threads; each thread sums 2 of the 2048 per-block slots,
// then the same shuffle/LDS reduction. Tail: 13 double logs run SIMT-concurrently.
__global__ __launch_bounds__(1024) void lfq_final(const float* __restrict__ part,
                                                  float* __restrict__ out) {
    const int t = threadIdx.x;  // 0..1023
    float vals[NACC];
    const float* p0 = part + (size_t)t * SLOT;
    const float* p1 = part + (size_t)(t + 1024) * SLOT;
#pragma unroll
    for (int k = 0; k < NACC; ++k) vals[k] = p0[k] + p1[k];
#pragma unroll
    for (int off = 32; off > 0; off >>= 1) {
#pragma unroll
        for (int k = 0; k < NACC; ++k) vals[k] += __shfl_down(vals[k], off);
    }
    __shared__ float red[1024 / 64][NACC];
    const int wave = t >> 6;
    const int lane = t & 63;
    if (lane == 0) {
#pragma unroll
        for (int k = 0; k < NACC; ++k) red[wave][k] = vals[k];
    }
    __syncthreads();
    __shared__ double accs[NACC];
    if (t < NACC) {
        double s = 0.0;
#pragma unroll
        for (int w = 0; w < 1024 / 64; ++w) s += (double)red[w][t];
        accs[t] = s;
    }
    __syncthreads();
    __shared__ double ment[C];
    if (t < C) {
        const double mp0 = accs[2 + t] / (double)NSAMP;
        const double mp1 = 1.0 - mp0;
        ment[t] = -(mp0 * log(mp0) + mp1 * log(mp1));  // 13 lanes, one SIMT log pass
    }
    __syncthreads();
    if (t == 0) {
        double me = 0.0;
#pragma unroll
        for (int c = 0; c < C; ++c) me += ment[c];
        me /= (double)C;
        const double commit = accs[0] / (double)NTOT;
        const double ent = accs[1] / (double)NTOT;
        out[COMMIT_OFF] = (float)(0.1 * 1.25 * commit);  // COMMIT_MULT * (1 + BETA)
        out[ENT_OFF] = (float)(0.1 * (ent - me));        // ENT_MULT
    }
}

extern "C" void kernel_launch(void* const* d_in, const int* in_sizes, int n_in,
                              void* d_out, int out_size, void* d_ws, size_t ws_size,
                              hipStream_t stream) {
    const float* z = (const float*)d_in[0];
    float* out = (float*)d_out;
    float* part = (float*)d_ws;

    lfq_main<<<NBLK, THREADS, 0, stream>>>(z, out, part);
    lfq_final<<<1, 1024, 0, stream>>>(part, out);
}